// Round 13
// baseline (236.076 us; speedup 1.0000x reference)
//
#include <hip/hip_runtime.h>
#include <hip/hip_cooperative_groups.h>
#include <stdint.h>

namespace cg = cooperative_groups;
typedef unsigned long long u64;

#define NB 2
#define N_ANCHORS 262144           // 2^18
#define PRE_NMS 6000
#define PROPOSALS 2000
#define NCHUNK 94                  // ceil(6000/64)
#define CAND_CAP 8192
#define HBINS 16384                // scores in (0,1) -> key>>16 < 16384
#define NBLK 256
#define NTHR 1024
#define HB_PER_B 64                // hist blocks per batch (blocks 0..127)
#define HB_CHUNK (N_ANCHORS / HB_PER_B)   // 4096 anchors
#define CB_PER_B 64
#define CB_CHUNK (N_ANCHORS / CB_PER_B)   // 4096
#define CBUF 512
#define WINDOW 2048
#define EDGE_CAP 65536
#define EBUF_IOU 2048
#define EBUF_FIX 8192
#define R4N 6                      // 1024-row blocks per column strip (6*1024 >= 6000)
#define COMBOS (NB * NCHUNK * R4N) // 1128 tile jobs

// ---- workspace layout (bytes) ----
#define OFF_HIST 0                                  // 131072 (zeroed in P1)
#define OFF_BCNT (NB*HBINS*4)                       // 131072 (zeroed in P1)
#define OFF_SCAL (2*NB*HBINS*4)                     // 64 B used (zeroed in P1)
#define OFF_CAND (OFF_SCAL + 256)                   // 131072 (guarded by totalCand)
#define OFF_SUFF (OFF_CAND + NB*CAND_CAP*8)         // 131072 (fully overwritten)
#define OFF_BOXES (OFF_SUFF + NB*HBINS*4)           // 192000 (ranks [0,6000) written)
#define OFF_EDGES (OFF_BOXES + NB*PRE_NMS*16)       // 524288 (guarded by edgeCount)

// scal per batch (8 ints): [2]=kthr(T<<16) [5]=edgeCount [6]=totalCand

__global__ __launch_bounds__(NTHR) void mega(const float4* __restrict__ probs4,
                                             const float* __restrict__ bbox,
                                             const float* __restrict__ anchors,
                                             char* __restrict__ ws,
                                             float4* __restrict__ out) {
    cg::grid_group grid = cg::this_grid();
    unsigned* hist   = (unsigned*)(ws + OFF_HIST);
    unsigned* binCnt = (unsigned*)(ws + OFF_BCNT);
    int* scal        = (int*)(ws + OFF_SCAL);
    u64* cand        = (u64*)(ws + OFF_CAND);
    unsigned* suff   = (unsigned*)(ws + OFF_SUFF);
    float4* boxes    = (float4*)(ws + OFF_BOXES);
    unsigned* edges  = (unsigned*)(ws + OFF_EDGES);

    __shared__ __align__(16) unsigned SH[HBINS];   // 64 KB, aliased per phase
    const int bid = blockIdx.x;
    const int t = threadIdx.x;

    // ================= P1: private LDS hist (blocks 0..127) =================
    //                    + zero hist/binCnt/scal (blocks 128..255)
    if (bid < NB * HB_PER_B) {
        for (int j = t; j < HBINS; j += NTHR) SH[j] = 0u;
        __syncthreads();
        int b = bid / HB_PER_B, blk = bid % HB_PER_B;
        const float4* p = probs4 + ((size_t)b * N_ANCHORS + (size_t)blk * HB_CHUNK) / 2;
        #pragma unroll
        for (int k = 0; k < HB_CHUNK / 2048; ++k) {      // 2 iters, 1 float4/thread
            float4 v = p[k * NTHR + t];
            unsigned b0 = __float_as_uint(v.y) >> 16;
            unsigned b1 = __float_as_uint(v.w) >> 16;
            if (b0 > HBINS - 1) b0 = HBINS - 1;
            if (b1 > HBINS - 1) b1 = HBINS - 1;
            atomicAdd(&SH[b0], 1u);
            atomicAdd(&SH[b1], 1u);
        }
        __syncthreads();
    } else {
        size_t idx = (size_t)(bid - NB * HB_PER_B) * NTHR + t;   // 0..131071
        if (idx < (size_t)NB * HBINS) hist[idx] = 0u;
        else if (idx < 2u * NB * HBINS) binCnt[idx - (size_t)NB * HBINS] = 0u;
        else if (idx < 2u * NB * HBINS + 16) scal[idx - 2u * NB * HBINS] = 0;
    }
    grid.sync();
    // ================= P2: merge LDS hists -> global hist ====================
    if (bid < NB * HB_PER_B) {
        int b = bid / HB_PER_B;
        unsigned* gh = hist + (size_t)b * HBINS;
        for (int j = t; j < HBINS; j += NTHR) {
            unsigned v = SH[j];
            if (v) atomicAdd(&gh[j], v);     // per-address chain depth <= 64
        }
    }
    grid.sync();
    // ================= P3: threshold select + suffix array ==================
    if (bid < NB) {
        int b = bid;
        const unsigned* h = hist + (size_t)b * HBINS;
        unsigned* sf = suff + (size_t)b * HBINS;
        unsigned bbase = t * 16;
        unsigned hl[16];
        unsigned s = 0;
        #pragma unroll
        for (int j = 0; j < 16; ++j) { hl[j] = h[bbase + j]; s += hl[j]; }
        SH[t] = s;
        __syncthreads();
        for (int off = 1; off < 1024; off <<= 1) {
            unsigned v = SH[t] + ((t + off < 1024) ? SH[t + off] : 0u);
            __syncthreads();
            SH[t] = v;
            __syncthreads();
        }
        unsigned run = (t < 1023) ? SH[t + 1] : 0u;   // keys in chunks > t
        #pragma unroll
        for (int j = 15; j >= 0; --j) { sf[bbase + j] = run; run += hl[j]; }
        unsigned sufInc = SH[t];
        unsigned sufBefore = sufInc - s;
        if (sufBefore < PRE_NMS && sufInc >= PRE_NMS) {   // unique crossing thread
            unsigned r2 = sufBefore, T = 0, totC = 0;
            for (int j = 15; j >= 0; --j) {
                if (r2 + hl[j] >= PRE_NMS) { T = bbase + j; totC = r2 + hl[j]; break; }
                r2 += hl[j];
            }
            if (totC > CAND_CAP) totC = CAND_CAP;
            scal[b * 8 + 2] = (int)(T << 16);
            scal[b * 8 + 6] = (int)totC;
        }
    }
    grid.sync();
    // ================= P4: windowed LDS-privatized compaction ================
    {
        unsigned* lcnt = SH;                       // [0..2047]
        u64* keyBuf = (u64*)&SH[2048];             // 512 u64 (byte 8192, 8-aligned)
        unsigned* slotBuf = &SH[3072];             // 512
        int* ncp = (int*)&SH[3584];
        if (bid < NB * CB_PER_B) {
            int b = bid / CB_PER_B, blk = bid % CB_PER_B;
            for (int j = t; j < WINDOW; j += NTHR) lcnt[j] = 0u;
            if (t == 0) *ncp = 0;
            __syncthreads();
            unsigned kthr = (unsigned)scal[b * 8 + 2];
            unsigned T = kthr >> 16;
            const unsigned* sfB = suff + (size_t)b * HBINS;
            unsigned* bcB = binCnt + (size_t)b * HBINS;
            u64* candB = cand + (size_t)b * CAND_CAP;
            size_t anchor0 = (size_t)blk * CB_CHUNK;
            const float4* p = probs4 + ((size_t)b * N_ANCHORS + anchor0) / 2;
            #pragma unroll
            for (int k = 0; k < CB_CHUNK / 2048; ++k) {   // 2 iters
                float4 v = p[k * NTHR + t];
                unsigned n0 = (unsigned)(anchor0 + ((size_t)(k * NTHR + t)) * 2);
                unsigned keys[2] = { __float_as_uint(v.y), __float_as_uint(v.w) };
                #pragma unroll
                for (int e = 0; e < 2; ++e) {
                    unsigned key = keys[e];
                    if (key >= kthr) {
                        unsigned bin = key >> 16;
                        unsigned rel = bin - T;
                        u64 k64 = ((u64)key << 32) | (u64)(~(n0 + e));
                        int idx;
                        if (rel < WINDOW && (idx = atomicAdd(ncp, 1)) < CBUF) {
                            unsigned slot = atomicAdd(&lcnt[rel], 1u);
                            keyBuf[idx] = k64;
                            slotBuf[idx] = slot;
                        } else {   // cold fallback: direct global allocation
                            unsigned gs = atomicAdd(&bcB[bin], 1u);
                            unsigned pos = sfB[bin] + gs;
                            if (pos < CAND_CAP) candB[pos] = k64;
                        }
                    }
                }
            }
            __syncthreads();
            for (int j = t; j < WINDOW; j += NTHR) {      // merge: lcnt <- global base
                unsigned c = lcnt[j];
                if (c) lcnt[j] = atomicAdd(&bcB[T + j], c);
            }
            __syncthreads();
            int tot = *ncp; if (tot > CBUF) tot = CBUF;
            for (int k = t; k < tot; k += NTHR) {
                u64 k64 = keyBuf[k];
                unsigned bin = (unsigned)(k64 >> 48);
                unsigned pos = sfB[bin] + lcnt[bin - T] + slotBuf[k];
                if (pos < CAND_CAP) candB[pos] = k64;
            }
        }
    }
    grid.sync();
    // ================= P5: wave-cooperative rank + decode ====================
    {
        int w = t >> 6, lane = t & 63;
        int g = bid * (NTHR / 64) + w;             // 0..4095
        for (int kk = 0; kk < 4; ++kk) {
            int job = g + kk * 4096;               // 0..16383
            int b = job >> 13;
            int p = job & (CAND_CAP - 1);
            if (p >= scal[b * 8 + 6]) continue;    // stale slot
            u64 my = cand[(size_t)b * CAND_CAP + p];
            unsigned bin = (unsigned)(my >> 48);
            unsigned s = suff[(size_t)b * HBINS + bin];
            if (s >= PRE_NMS) continue;
            unsigned c = binCnt[(size_t)b * HBINS + bin];
            if (s + c > CAND_CAP) c = CAND_CAP - s;
            const u64* seg = cand + (size_t)b * CAND_CAP + s;
            int cnt = 0;
            for (unsigned q = lane; q < c; q += 64) cnt += (seg[q] > my) ? 1 : 0;
            #pragma unroll
            for (int off = 32; off; off >>= 1) cnt += __shfl_down(cnt, off, 64);
            int rank = (int)s + __shfl(cnt, 0, 64);
            if (rank < PRE_NMS && lane == 0) {
                int n = (int)(~(unsigned)(my & 0xFFFFFFFFull));
                const float4* anch4 = (const float4*)anchors + (size_t)b * N_ANCHORS;
                const float4* bb4   = (const float4*)bbox    + (size_t)b * N_ANCHORS;
                float4 a  = anch4[n];
                float4 dd = bb4[n];
                float d0 = dd.x * 0.1f, d1 = dd.y * 0.1f;
                float d2 = dd.z * 0.2f, d3 = dd.w * 0.2f;
                float h = a.z - a.x, wd = a.w - a.y;
                float cy = a.x + 0.5f * h + d0 * h;
                float cx = a.y + 0.5f * wd + d1 * wd;
                h = h * expf(d2);
                wd = wd * expf(d3);
                float y1 = cy - 0.5f * h, x1 = cx - 0.5f * wd;
                float y2 = y1 + h,        x2 = x1 + wd;
                y1 = fminf(fmaxf(y1, 0.f), 1.f);
                x1 = fminf(fmaxf(x1, 0.f), 1.f);
                y2 = fminf(fmaxf(y2, 0.f), 1.f);
                x2 = fminf(fmaxf(x2, 0.f), 1.f);
                boxes[(size_t)b * PRE_NMS + rank] = make_float4(y1, x1, y2, x2);
            }
        }
    }
    grid.sync();
    // ================= P6: sparse IoU edges (tile jobs) ======================
    {
        float4* cb = (float4*)&SH[0];              // 64
        float* ca = (float*)&SH[256];              // 64
        unsigned* ebuf = &SH[320];                 // 2048
        int* nep = (int*)&SH[2368];
        int* ebp = (int*)&SH[2369];
        for (int combo = bid; combo < COMBOS; combo += NBLK) {   // block-uniform
            int b = combo / (NCHUNK * R4N);
            int rem = combo - b * (NCHUNK * R4N);
            int c = rem / R4N;
            int r4 = rem - c * R4N;
            int rowBase = r4 * 1024;
            if (rowBase >= (c + 1) * 64) continue;   // below diagonal: no i<j pairs
            const float4* bx = boxes + (size_t)b * PRE_NMS;
            __syncthreads();                         // protect prior tile's buffers
            if (t == 0) *nep = 0;
            if (t < 64) {
                int col = c * 64 + t;
                float4 v = (col < PRE_NMS) ? bx[col] : make_float4(2.f, 2.f, 2.f, 2.f);
                cb[t] = v;
                ca[t] = (v.z - v.x) * (v.w - v.y);
            }
            __syncthreads();
            int i = rowBase + t;
            if (i < PRE_NMS) {
                int rel = i - c * 64;
                u64 maskGT = (rel < 0) ? ~0ull : ((rel >= 63) ? 0ull : ~((2ull << rel) - 1ull));
                if (maskGT) {
                    float4 bi = bx[i];
                    float ai = (bi.z - bi.x) * (bi.w - bi.y);
                    u64 m = 0ull;
                    #pragma unroll
                    for (int j = 0; j < 64; ++j) {
                        float4 bj = cb[j];
                        float iy1 = fmaxf(bi.x, bj.x);
                        float ix1 = fmaxf(bi.y, bj.y);
                        float iy2 = fminf(bi.z, bj.z);
                        float ix2 = fminf(bi.w, bj.w);
                        float inter = fmaxf(iy2 - iy1, 0.f) * fmaxf(ix2 - ix1, 0.f);
                        float uni = ai + ca[j] - inter;
                        // iou>0.7 <=> inter>0.7*uni (uni>=0; uni==0 -> inter==0)
                        if (inter > 0.7f * uni) m |= (1ull << j);
                    }
                    m &= maskGT;
                    while (m) {                      // rare (~600 edges total)
                        int j = __ffsll((long long)m) - 1;
                        m &= m - 1;
                        unsigned e = ((unsigned)(c * 64 + j) << 16) | (unsigned)i;
                        int idx = atomicAdd(nep, 1); // LDS atomic
                        if (idx < EBUF_IOU) ebuf[idx] = e;
                        else {                       // cold overflow
                            int pos = atomicAdd(&scal[b * 8 + 5], 1);
                            if (pos < EDGE_CAP) edges[(size_t)b * EDGE_CAP + pos] = e;
                        }
                    }
                }
            }
            __syncthreads();
            int cnt = *nep; if (cnt > EBUF_IOU) cnt = EBUF_IOU;
            if (t == 0 && cnt) *ebp = atomicAdd(&scal[b * 8 + 5], cnt);  // 1/tile
            __syncthreads();
            for (int k = t; k < cnt; k += NTHR) {
                int pos = *ebp + k;
                if (pos < EDGE_CAP) edges[(size_t)b * EDGE_CAP + pos] = ebuf[k];
            }
        }
    }
    grid.sync();
    // ================= P7: greedy-NMS fixpoint + writeout ====================
    if (bid < NB) {
        int b = bid;
        u64* S    = (u64*)&SH[0];                  // 94
        u64* Snew = (u64*)&SH[188];                // 94 (byte 752, 8-aligned)
        int* pref = (int*)&SH[376];                // 94
        int* chp  = (int*)&SH[472];
        int* tkp  = (int*)&SH[473];
        unsigned* ebufL = &SH[512];                // 8192
        const unsigned* egB = edges + (size_t)b * EDGE_CAP;
        int E = scal[b * 8 + 5];
        if (E > EDGE_CAP) E = EDGE_CAP;
        int Es = E < EBUF_FIX ? E : EBUF_FIX;
        for (int k = t; k < Es; k += NTHR) ebufL[k] = egB[k];
        for (int w = t; w < NCHUNK; w += NTHR) S[w] = 0ull;
        __syncthreads();
        if (E > 0) {
            for (int it = 0; it < PRE_NMS + 1; ++it) {
                for (int w = t; w < NCHUNK; w += NTHR) Snew[w] = 0ull;
                if (t == 0) *chp = 0;
                __syncthreads();
                for (int k = t; k < E; k += NTHR) {
                    unsigned e = (k < Es) ? ebufL[k] : egB[k];
                    int i = (int)(e & 0xFFFFu), j = (int)(e >> 16);
                    if (!((S[i >> 6] >> (i & 63)) & 1ull))
                        atomicOr(&Snew[j >> 6], 1ull << (j & 63));
                }
                __syncthreads();
                int ch = 0;
                for (int w = t; w < NCHUNK; w += NTHR) {
                    if (Snew[w] != S[w]) { ch = 1; S[w] = Snew[w]; }
                }
                if (ch) *chp = 1;
                __syncthreads();
                if (!*chp) break;
                __syncthreads();
            }
        }
        __syncthreads();
        for (int w = t; w < NCHUNK; w += NTHR) {
            u64 valid = (w < NCHUNK - 1) ? ~0ull
                        : ((1ull << (PRE_NMS - (NCHUNK - 1) * 64)) - 1ull);
            Snew[w] = (~S[w]) & valid;             // keep bitset
        }
        __syncthreads();
        if (t == 0) {
            int run = 0;
            for (int w = 0; w < NCHUNK; ++w) { pref[w] = run; run += __popcll(Snew[w]); }
            *tkp = (run < PROPOSALS) ? run : PROPOSALS;
        }
        __syncthreads();
        const float4* bx = boxes + (size_t)b * PRE_NMS;
        float4* ob = out + (size_t)b * PROPOSALS;
        if (t < NCHUNK) {
            u64 k = Snew[t];
            int pos = pref[t];
            while (k && pos < PROPOSALS) {
                int l = __ffsll((long long)k) - 1;
                k &= k - 1;
                ob[pos++] = bx[t * 64 + l];
            }
        }
        int tk = *tkp;
        for (int q = tk + t; q < PROPOSALS; q += NTHR)
            ob[q] = make_float4(0.f, 0.f, 0.f, 0.f);
    }
}

extern "C" void kernel_launch(void* const* d_in, const int* in_sizes, int n_in,
                              void* d_out, int out_size, void* d_ws, size_t ws_size,
                              hipStream_t stream) {
    (void)in_sizes; (void)n_in; (void)out_size; (void)ws_size;
    const float4* probs4 = (const float4*)d_in[0];
    const float* bbox    = (const float*)d_in[1];
    const float* anchors = (const float*)d_in[2];
    char* ws = (char*)d_ws;
    float4* outp = (float4*)d_out;
    void* args[] = { (void*)&probs4, (void*)&bbox, (void*)&anchors,
                     (void*)&ws, (void*)&outp };
    hipLaunchCooperativeKernel((const void*)mega, dim3(NBLK), dim3(NTHR),
                               args, 0, stream);
}

// Round 14
// 75.954 us; speedup vs baseline: 3.1082x; 3.1082x over previous
//
#include <hip/hip_runtime.h>
#include <stdint.h>

typedef unsigned long long u64;

#define NB 2
#define N_ANCHORS 262144           // 2^18
#define PRE_NMS 6000
#define PROPOSALS 2000
#define NCHUNK 94                  // ceil(6000/64) words in keep/suppress bitset
#define CAND_CAP 8192
#define HBINS 16384                // scores in (0,1) -> key>>16 <= 0x3F80 < 16384
#define HB_BLOCKS_PER_B 32
#define HB_CHUNK (N_ANCHORS / HB_BLOCKS_PER_B)   // 8192
#define HR_BLOCKS_PER_B 16         // reduce blocks per batch (1024 bins each)
#define CB_BLOCKS_PER_B 64
#define CB_CHUNK (N_ANCHORS / CB_BLOCKS_PER_B)   // 4096
#define CBUF 512
#define WINDOW 2048                // candidate bins span ~17 bins here; 2048 is ample
#define EDGE_CAP 65536
#define EDGE_LDS 16384
#define IOU_RB ((PRE_NMS + 255) / 256)           // 24 row blocks

// ---- workspace layout (bytes) ---- no pre-zero kernel: hrows/hist/suff fully
// overwritten; doneReduce zeroed by K1; binCnt+edgeCnt zeroed by K2-lastblock;
// cand guarded by totalCand; boxes ranks [0,6000) all written; edges by edgeCount.
#define OFF_HIST 0                                  // 131072
#define OFF_BCNT (NB*HBINS*4)                       // 131072
#define OFF_SCAL (2*NB*HBINS*4)                     // 256
#define OFF_CAND (OFF_SCAL + 256)                   // 131072
#define OFF_SUFF (OFF_CAND + NB*CAND_CAP*8)         // 131072
#define OFF_BOXES (OFF_SUFF + NB*HBINS*4)           // 192000
#define OFF_EDGES (OFF_BOXES + NB*PRE_NMS*16)       // 524288
#define OFF_HROWS (OFF_EDGES + NB*EDGE_CAP*4)       // NB*32*16384*4 = 4.2 MB

// scal per batch (8 ints): [0]=doneReduce [2]=kthr(T<<16) [5]=edgeCount
//                          [6]=totalCand

// K1: per-block private LDS histogram -> private global row. Block 0 of each
// batch zeroes the doneReduce counter (stream-ordered before K2 uses it).
__global__ __launch_bounds__(1024) void hist_kernel(const float4* __restrict__ probs4,
                                                    unsigned* __restrict__ hrows,
                                                    int* __restrict__ scal) {
    __shared__ unsigned lh[HBINS];
    int t = threadIdx.x;
    for (int j = t; j < HBINS; j += 1024) lh[j] = 0u;
    int b   = blockIdx.x / HB_BLOCKS_PER_B;
    int blk = blockIdx.x % HB_BLOCKS_PER_B;
    if (blk == 0 && t == 0) scal[b * 8 + 0] = 0;
    __syncthreads();
    // float4 = 2 (prob0, prob1) pairs; keys are .y and .w
    const float4* p = probs4 + ((size_t)b * N_ANCHORS + (size_t)blk * HB_CHUNK) / 2;
    #pragma unroll
    for (int k = 0; k < HB_CHUNK / 2048; ++k) {     // 4 iters
        float4 v = p[k * 1024 + t];
        unsigned bin0 = __float_as_uint(v.y) >> 16;
        unsigned bin1 = __float_as_uint(v.w) >> 16;
        if (bin0 > HBINS - 1) bin0 = HBINS - 1;
        if (bin1 > HBINS - 1) bin1 = HBINS - 1;
        atomicAdd(&lh[bin0], 1u);
        atomicAdd(&lh[bin1], 1u);
    }
    __syncthreads();
    unsigned* row = hrows + (size_t)(b * HB_BLOCKS_PER_B + blk) * HBINS;
    for (int j = t; j < HBINS; j += 1024) row[j] = lh[j];
}

// K2: row reduce (16 blocks/batch, 1 bin/thread, coalesced) + per-batch
// LAST BLOCK (16-deep counter chain: harmless) runs threshold-select +
// suffix array + binCnt/edgeCnt zeroing.
__global__ __launch_bounds__(1024) void reduce_scan(const unsigned* __restrict__ hrows,
                                                    unsigned* __restrict__ hist,
                                                    int* __restrict__ scal,
                                                    unsigned* __restrict__ suff,
                                                    unsigned* __restrict__ binCnt) {
    int t = threadIdx.x;
    int b   = blockIdx.x / HR_BLOCKS_PER_B;
    int blk = blockIdx.x % HR_BLOCKS_PER_B;
    int bin = blk * 1024 + t;
    const unsigned* base = hrows + (size_t)b * HB_BLOCKS_PER_B * HBINS + bin;
    unsigned s0 = 0;
    #pragma unroll
    for (int r = 0; r < HB_BLOCKS_PER_B; ++r) s0 += base[(size_t)r * HBINS];
    hist[(size_t)b * HBINS + bin] = s0;
    __shared__ int amLast;
    __syncthreads();
    if (t == 0) {
        __threadfence();
        amLast = (atomicAdd(&scal[b * 8 + 0], 1) == HR_BLOCKS_PER_B - 1);
    }
    __syncthreads();
    if (!amLast) return;
    __threadfence();
    // ---- scan body (1024 threads, 16 bins each) ----
    const unsigned* h = hist + (size_t)b * HBINS;
    unsigned* sf = suff + (size_t)b * HBINS;
    unsigned* bc = binCnt + (size_t)b * HBINS;
    for (int j = t; j < HBINS; j += 1024) bc[j] = 0u;   // zero binCnt (pre-compact)
    if (t == 0) scal[b * 8 + 5] = 0;                    // zero edge counter
    unsigned bbase = t * 16;
    unsigned hl[16];
    unsigned s = 0;
    #pragma unroll
    for (int j = 0; j < 16; ++j) { hl[j] = h[bbase + j]; s += hl[j]; }
    __shared__ unsigned buf[1024];
    buf[t] = s;
    __syncthreads();
    for (int off = 1; off < 1024; off <<= 1) {
        unsigned v = buf[t] + ((t + off < 1024) ? buf[t + off] : 0u);
        __syncthreads();
        buf[t] = v;
        __syncthreads();
    }
    // buf[k] = suffix sum over chunks >= k
    unsigned run = (t < 1023) ? buf[t + 1] : 0u;   // keys in chunks > t
    #pragma unroll
    for (int j = 15; j >= 0; --j) {
        sf[bbase + j] = run;          // strictly-greater-bin count
        run += hl[j];
    }
    unsigned sufInc = buf[t];
    unsigned sufBefore = sufInc - s;
    if (sufBefore < PRE_NMS && sufInc >= PRE_NMS) {   // unique crossing thread
        unsigned r2 = sufBefore;
        unsigned T = 0, totC = 0;
        for (int j = 15; j >= 0; --j) {
            if (r2 + hl[j] >= PRE_NMS) { T = bbase + j; totC = r2 + hl[j]; break; }
            r2 += hl[j];
        }
        if (totC > CAND_CAP) totC = CAND_CAP;
        scal[b * 8 + 2] = (int)(T << 16);   // compact threshold
        scal[b * 8 + 6] = (int)totC;        // total candidates (cand[0..totC) valid)
    }
}

// K3: windowed LDS-privatized compaction (measured good, unchanged).
__global__ __launch_bounds__(256) void compact(const float4* __restrict__ probs4,
                                               const int* __restrict__ scal,
                                               const unsigned* __restrict__ suff,
                                               unsigned* __restrict__ binCnt,
                                               u64* __restrict__ cand) {
    __shared__ unsigned lcnt[WINDOW];    // pass A: local count; pass B: global base
    __shared__ u64 keyBuf[CBUF];
    __shared__ unsigned slotBuf[CBUF];
    __shared__ int nc;
    int t = threadIdx.x;
    int b   = blockIdx.x / CB_BLOCKS_PER_B;
    int blk = blockIdx.x % CB_BLOCKS_PER_B;
    for (int j = t; j < WINDOW; j += 256) lcnt[j] = 0u;
    if (t == 0) nc = 0;
    __syncthreads();
    unsigned kthr = (unsigned)scal[b * 8 + 2];
    unsigned T = kthr >> 16;
    const unsigned* sfB = suff + (size_t)b * HBINS;
    unsigned* bcB = binCnt + (size_t)b * HBINS;
    u64* candB = cand + (size_t)b * CAND_CAP;
    size_t anchor0 = (size_t)blk * CB_CHUNK;
    const float4* p = probs4 + ((size_t)b * N_ANCHORS + anchor0) / 2;
    #pragma unroll 2
    for (int k = 0; k < CB_CHUNK / 512; ++k) {
        float4 v = p[k * 256 + t];
        unsigned n0 = (unsigned)(anchor0 + ((size_t)(k * 256 + t)) * 2);
        unsigned keys[2] = { __float_as_uint(v.y), __float_as_uint(v.w) };
        #pragma unroll
        for (int e = 0; e < 2; ++e) {
            unsigned key = keys[e];
            if (key >= kthr) {
                unsigned bin = key >> 16;
                unsigned rel = bin - T;                   // key>=kthr -> bin>=T
                u64 k64 = ((u64)key << 32) | (u64)(~(n0 + e));
                int idx;
                if (rel < WINDOW && (idx = atomicAdd(&nc, 1)) < CBUF) {
                    unsigned slot = atomicAdd(&lcnt[rel], 1u);
                    keyBuf[idx] = k64;
                    slotBuf[idx] = slot;
                } else {   // overflow fallback: direct global allocation (correct, slow)
                    unsigned gs = atomicAdd(&bcB[bin], 1u);
                    unsigned pos = sfB[bin] + gs;
                    if (pos < CAND_CAP) candB[pos] = k64;
                }
            }
        }
    }
    __syncthreads();
    for (int j = t; j < WINDOW; j += 256) {    // pass B: merge, lcnt <- global base
        unsigned c = lcnt[j];
        if (c) lcnt[j] = atomicAdd(&bcB[T + j], c);
    }
    __syncthreads();
    int tot = nc < CBUF ? nc : CBUF;           // pass C: scatter
    for (int k = t; k < tot; k += 256) {
        u64 k64 = keyBuf[k];
        unsigned bin = (unsigned)(k64 >> 48);
        unsigned pos = sfB[bin] + lcnt[bin - T] + slotBuf[k];
        if (pos < CAND_CAP) candB[pos] = k64;
    }
}

// K4: wave-cooperative within-bin ranking + decode (measured good, unchanged).
__global__ __launch_bounds__(256) void refine_decode(const u64* __restrict__ cand,
                                                     const int* __restrict__ scal,
                                                     const unsigned* __restrict__ suff,
                                                     const unsigned* __restrict__ binCnt,
                                                     const float* __restrict__ anchors,
                                                     const float* __restrict__ bbox,
                                                     float4* __restrict__ boxes) {
    int b = blockIdx.y;
    int wave = threadIdx.x >> 6;
    int lane = threadIdx.x & 63;
    int p = blockIdx.x * 4 + wave;                     // candidate slot 0..8191
    if (p >= scal[b * 8 + 6]) return;                  // beyond totalCand: stale slot
    u64 my = cand[(size_t)b * CAND_CAP + p];           // wave-uniform broadcast
    unsigned bin = (unsigned)(my >> 48);
    unsigned s = suff[(size_t)b * HBINS + bin];
    if (s >= PRE_NMS) return;                          // entire segment beyond cutoff
    unsigned c = binCnt[(size_t)b * HBINS + bin];
    if (s + c > CAND_CAP) c = CAND_CAP - s;
    const u64* seg = cand + (size_t)b * CAND_CAP + s;
    int cnt = 0;
    for (unsigned q = lane; q < c; q += 64)            // coalesced 512B/iter
        cnt += (seg[q] > my) ? 1 : 0;
    #pragma unroll
    for (int off = 32; off; off >>= 1) cnt += __shfl_down(cnt, off, 64);
    int rank = (int)s + __shfl(cnt, 0, 64);
    if (rank < PRE_NMS && lane == 0) {
        int n = (int)(~(unsigned)(my & 0xFFFFFFFFull));
        const float4* anch4 = (const float4*)anchors + (size_t)b * N_ANCHORS;
        const float4* bb4   = (const float4*)bbox    + (size_t)b * N_ANCHORS;
        float4 a  = anch4[n];
        float4 dd = bb4[n];
        float d0 = dd.x * 0.1f, d1 = dd.y * 0.1f;
        float d2 = dd.z * 0.2f, d3 = dd.w * 0.2f;
        float h = a.z - a.x, w = a.w - a.y;
        float cy = a.x + 0.5f * h + d0 * h;
        float cx = a.y + 0.5f * w + d1 * w;
        h = h * expf(d2);
        w = w * expf(d3);
        float y1 = cy - 0.5f * h, x1 = cx - 0.5f * w;
        float y2 = y1 + h,        x2 = x1 + w;
        y1 = fminf(fmaxf(y1, 0.f), 1.f);
        x1 = fminf(fmaxf(x1, 0.f), 1.f);
        y2 = fminf(fmaxf(y2, 0.f), 1.f);
        x2 = fminf(fmaxf(x2, 0.f), 1.f);
        boxes[(size_t)b * PRE_NMS + rank] = make_float4(y1, x1, y2, x2);
    }
}

// K5: sparse IoU edges, R9-proven shape (per-edge global atomic append —
// empirically faster than every avoidance scheme tried in R10-R12).
__global__ __launch_bounds__(256) void iou_edges(const float4* __restrict__ boxes,
                                                 int* __restrict__ scal,
                                                 unsigned* __restrict__ edges) {
    int c  = blockIdx.x;     // column chunk 0..93
    int rb = blockIdx.y;     // row block 0..23
    int b  = blockIdx.z;
    int rowBase = rb * 256;
    if (rowBase >= (c + 1) * 64) return;     // all rows > all cols -> no i<j pairs
    const float4* bx = boxes + (size_t)b * PRE_NMS;
    __shared__ float4 cb[64];
    __shared__ float  ca[64];
    int t = threadIdx.x;
    if (t < 64) {
        int col = c * 64 + t;
        float4 v = (col < PRE_NMS) ? bx[col] : make_float4(2.f, 2.f, 2.f, 2.f);
        cb[t] = v;
        ca[t] = (v.z - v.x) * (v.w - v.y);
    }
    __syncthreads();
    int i = rowBase + t;
    if (i >= PRE_NMS) return;
    int rel = i - c * 64;
    u64 maskGT = (rel < 0) ? ~0ull : ((rel >= 63) ? 0ull : ~((2ull << rel) - 1ull));
    if (!maskGT) return;
    float4 bi = bx[i];
    float ai = (bi.z - bi.x) * (bi.w - bi.y);
    u64 m = 0ull;
    #pragma unroll
    for (int j = 0; j < 64; ++j) {
        float4 bj = cb[j];
        float iy1 = fmaxf(bi.x, bj.x);
        float ix1 = fmaxf(bi.y, bj.y);
        float iy2 = fminf(bi.z, bj.z);
        float ix2 = fminf(bi.w, bj.w);
        float inter = fmaxf(iy2 - iy1, 0.f) * fmaxf(ix2 - ix1, 0.f);
        float uni = ai + ca[j] - inter;
        // iou > 0.7  <=>  inter > 0.7*uni  (uni>=0; uni==0 -> inter==0 -> false)
        if (inter > 0.7f * uni) m |= (1ull << j);
    }
    m &= maskGT;
    while (m) {                               // rare (~600 edges total per batch)
        int j = __ffsll((long long)m) - 1;
        m &= m - 1;
        int col = c * 64 + j;
        int pos = atomicAdd(&scal[b * 8 + 5], 1);
        if (pos < EDGE_CAP)
            edges[(size_t)b * EDGE_CAP + pos] = ((unsigned)col << 16) | (unsigned)i;
    }
}

// K6: exact greedy NMS as fixpoint of S[j] = exists edge (i,j) with i kept.
// Edges point forward (i<j) -> well-founded -> unique fixpoint = greedy result.
__global__ __launch_bounds__(256) void nms_fix(const unsigned* __restrict__ edges,
                                               const int* __restrict__ scal,
                                               const float4* __restrict__ boxes,
                                               float4* __restrict__ out) {
    int b = blockIdx.x;
    int t = threadIdx.x;
    int E = scal[b * 8 + 5];
    if (E > EDGE_CAP) E = EDGE_CAP;
    __shared__ u64 S[NCHUNK];
    __shared__ u64 Snew[NCHUNK];
    __shared__ unsigned eL[EDGE_LDS];
    __shared__ int changed;
    __shared__ int pref[NCHUNK];
    __shared__ int totalKept;
    const unsigned* eg = edges + (size_t)b * EDGE_CAP;
    bool staged = (E <= EDGE_LDS);
    if (staged) for (int k = t; k < E; k += 256) eL[k] = eg[k];
    for (int w = t; w < NCHUNK; w += 256) S[w] = 0ull;
    __syncthreads();
    if (E > 0) {
        for (int it = 0; it < PRE_NMS + 1; ++it) {
            for (int w = t; w < NCHUNK; w += 256) Snew[w] = 0ull;
            if (t == 0) changed = 0;
            __syncthreads();
            for (int k = t; k < E; k += 256) {
                unsigned e = staged ? eL[k] : eg[k];
                int i = (int)(e & 0xFFFFu), j = (int)(e >> 16);
                if (!((S[i >> 6] >> (i & 63)) & 1ull))
                    atomicOr(&Snew[j >> 6], 1ull << (j & 63));
            }
            __syncthreads();
            int ch = 0;
            for (int w = t; w < NCHUNK; w += 256) {
                if (Snew[w] != S[w]) { ch = 1; S[w] = Snew[w]; }
            }
            if (ch) changed = 1;
            __syncthreads();
            if (!changed) break;
        }
    }
    for (int w = t; w < NCHUNK; w += 256) {
        u64 valid = (w < NCHUNK - 1) ? ~0ull : ((1ull << (PRE_NMS - (NCHUNK - 1) * 64)) - 1ull);
        Snew[w] = (~S[w]) & valid;            // keep bitset
    }
    __syncthreads();
    if (t == 0) {
        int run = 0;
        for (int w = 0; w < NCHUNK; ++w) { pref[w] = run; run += __popcll(Snew[w]); }
        totalKept = (run < PROPOSALS) ? run : PROPOSALS;
    }
    __syncthreads();
    const float4* bx = boxes + (size_t)b * PRE_NMS;
    float4* ob = out + (size_t)b * PROPOSALS;
    if (t < NCHUNK) {
        u64 k = Snew[t];
        int pos = pref[t];
        while (k && pos < PROPOSALS) {
            int l = __ffsll((long long)k) - 1;
            k &= k - 1;
            ob[pos++] = bx[t * 64 + l];
        }
    }
    int tk = totalKept;
    for (int q = tk + t; q < PROPOSALS; q += 256)
        ob[q] = make_float4(0.f, 0.f, 0.f, 0.f);
}

extern "C" void kernel_launch(void* const* d_in, const int* in_sizes, int n_in,
                              void* d_out, int out_size, void* d_ws, size_t ws_size,
                              hipStream_t stream) {
    (void)in_sizes; (void)n_in; (void)out_size; (void)ws_size;
    const float4* probs4 = (const float4*)d_in[0];
    const float* bbox    = (const float*)d_in[1];
    const float* anchors = (const float*)d_in[2];
    char* ws = (char*)d_ws;
    unsigned* hist   = (unsigned*)(ws + OFF_HIST);
    unsigned* binCnt = (unsigned*)(ws + OFF_BCNT);
    int* scal        = (int*)(ws + OFF_SCAL);
    u64* cand        = (u64*)(ws + OFF_CAND);
    unsigned* suff   = (unsigned*)(ws + OFF_SUFF);
    float4* boxes    = (float4*)(ws + OFF_BOXES);
    unsigned* edges  = (unsigned*)(ws + OFF_EDGES);
    unsigned* hrows  = (unsigned*)(ws + OFF_HROWS);

    hist_kernel<<<NB * HB_BLOCKS_PER_B, 1024, 0, stream>>>(probs4, hrows, scal);
    reduce_scan<<<NB * HR_BLOCKS_PER_B, 1024, 0, stream>>>(hrows, hist, scal, suff, binCnt);
    compact<<<NB * CB_BLOCKS_PER_B, 256, 0, stream>>>(probs4, scal, suff, binCnt, cand);
    refine_decode<<<dim3(CAND_CAP / 4, NB), 256, 0, stream>>>(cand, scal, suff, binCnt,
                                                              anchors, bbox, boxes);
    iou_edges<<<dim3(NCHUNK, IOU_RB, NB), 256, 0, stream>>>(boxes, scal, edges);
    nms_fix<<<NB, 256, 0, stream>>>(edges, scal, boxes, (float4*)d_out);
}